// Round 1
// baseline (31211.859 us; speedup 1.0000x reference)
//
#include <hip/hip_runtime.h>

#define TSTEPS 2048
#define VDIM 128
#define FDIM 512

typedef __attribute__((ext_vector_type(8))) _Float16 half8;
typedef __attribute__((ext_vector_type(4))) _Float16 half4;
typedef __attribute__((ext_vector_type(4))) float floatx4;

// ws layout (bytes):
//   [0,       512K)  WH  : f16 hi, A-frag order: [wf32][kk16][lane64][e8]
//   [512K,   1024K)  WL  : f16 lo*4096, same order
//   [1024K,  1280K)  rH  : f16 hi   [buf2][g8][row16][k512]
//   [1280K,  1536K)  rL  : f16 lo*4096, same
//   [1536K,  1600K)  cnt : u32 [g8][t2048]
#define WS_WH   0
#define WS_WL   (512u * 1024u)
#define WS_RH   (1024u * 1024u)
#define WS_RL   (1280u * 1024u)
#define WS_CNT  (1536u * 1024u)

// Pre-swizzle W (fp32 row-major [j][k]) into per-wave A-fragment order, split
// into f16 hi + f16 lo*4096.  A-frag (16x16x32): lane l holds row (l&15),
// k = 8*(l>>4) + e within each K=32 block kk.
__global__ __launch_bounds__(256) void rnn_prep(const float* __restrict__ W,
                                                _Float16* __restrict__ WH,
                                                _Float16* __restrict__ WL) {
  int tid = blockIdx.x * 256 + threadIdx.x;   // 0..32767 (32 wf * 16 kk * 64 l)
  int wf = tid >> 10;
  int kk = (tid >> 6) & 15;
  int l  = tid & 63;
  int j  = 16 * wf + (l & 15);
  int k0 = kk * 32 + (l >> 4) * 8;
  const float* src = W + j * FDIM + k0;
  half8 vh, vl;
#pragma unroll
  for (int e = 0; e < 8; ++e) {
    float w = src[e];
    _Float16 h = (_Float16)w;
    vh[e] = h;
    vl[e] = (_Float16)((w - (float)h) * 4096.0f);
  }
  *(half8*)(WH + (size_t)tid * 8) = vh;
  *(half8*)(WL + (size_t)tid * 8) = vl;
}

// 64 WGs = 8 row-groups (g) x 8 feature-slices (s).  256 thr = 4 waves, each
// wave owns 16 output features (wf = s*4+w, features [16wf,16wf+16)) for all
// 16 rows of its group, with its W slice resident in VGPRs.
// MFMA orientation: D[j][i] = sum_k W[j][k] * r[i][k]  (A=W, B=r).
// D layout: col(l&15)=i (state row), row((l>>4)*4+v)=j (feature).
__global__ void __launch_bounds__(256, 1)
rnn_main(const float* __restrict__ X, const float* __restrict__ bvec,
         const _Float16* __restrict__ WH, const _Float16* __restrict__ WL,
         _Float16* __restrict__ rH, _Float16* __restrict__ rL,
         unsigned int* __restrict__ cnt, float* __restrict__ out) {
  const int g  = blockIdx.x & 7;
  const int w  = threadIdx.x >> 6;
  const int l  = threadIdx.x & 63;
  const int wf = (blockIdx.x >> 3) * 4 + w;   // 0..31
  const int lr = l & 15;                      // state row within group (D col)
  const int lg = l >> 4;                      // lane group
  const int jb = 16 * wf + lg * 4;            // this lane's 4 features jb..jb+3

  // persistent W fragments (hi + lo): 128 VGPRs
  half8 whf[16], wlf[16];
  {
    const half8* p = (const half8*)WH + wf * 16 * 64 + l;
    const half8* q = (const half8*)WL + wf * 16 * 64 + l;
#pragma unroll
    for (int kk = 0; kk < 16; ++kk) { whf[kk] = p[kk * 64]; wlf[kk] = q[kk * 64]; }
  }
  const floatx4 bv = *(const floatx4*)(bvec + jb);
  unsigned int* mycnt = cnt + g * TSTEPS;
  const bool vis = (wf < 8);          // jb < 128  <=> visible features
  const bool diagWave = (wf == g);    // wave holding group g's diagonal cols
  int budget = 4000000;               // anti-deadlock spin budget (never hit normally)

  for (int t = 0; t < TSTEPS; ++t) {
    floatx4 xv = {0.f, 0.f, 0.f, 0.f};
    if (vis) xv = *(const floatx4*)(X + t * VDIM + jb);

    if (t > 0) {
      while (__hip_atomic_load(mycnt + (t - 1), __ATOMIC_RELAXED,
                               __HIP_MEMORY_SCOPE_AGENT) < 8u) {
        if (--budget < 0) break;
        __builtin_amdgcn_s_sleep(1);
      }
      __threadfence();   // acquire: invalidate stale cached r lines
    }

    // B-frags: lane l reads r[group][row lr][k = kk*32 + lg*8 + e]
    const int roff = ((t & 1) * 8 + g) * (16 * FDIM) + lr * FDIM + lg * 8;
    const _Float16* ph = rH + roff;
    const _Float16* pl = rL + roff;
    floatx4 aHH = {0.f,0.f,0.f,0.f}, aLH = {0.f,0.f,0.f,0.f}, aHL = {0.f,0.f,0.f,0.f};
#pragma unroll
    for (int kk = 0; kk < 16; ++kk) {
      half8 bh = *(const half8*)(ph + kk * 32);
      half8 bl = *(const half8*)(pl + kk * 32);
      aHH = __builtin_amdgcn_mfma_f32_16x16x32_f16(whf[kk], bh, aHH, 0, 0, 0);
      aLH = __builtin_amdgcn_mfma_f32_16x16x32_f16(wlf[kk], bh, aLH, 0, 0, 0);
      aHL = __builtin_amdgcn_mfma_f32_16x16x32_f16(whf[kk], bl, aHL, 0, 0, 0);
    }

    const bool last = (t == TSTEPS - 1);
    half4 sh, sl;
#pragma unroll
    for (int v = 0; v < 4; ++v) {
      // lo products carry a 4096 prescale on exactly one operand
      float u = (aHH[v] + (aLH[v] + aHL[v]) * 2.44140625e-4f) + bv[v];
      if (vis) {
        float blend = 0.5f * u + 0.5f * xv[v];
        bool isdiag = diagWave && (lg * 4 + v == lr);
        if (!isdiag) u = blend;      // diag: Lambda=1, keep u = WR + b
      }
      if (last) {
        if (diagWave && (lg * 4 + v == lr)) out[16 * g + lr] = u;  // pre-tanh
      } else {
        float au = fabsf(u);
        float e2 = __expf(-2.0f * au);
        float th = __fdividef(1.0f - e2, 1.0f + e2);
        th = copysignf(th, u);
        _Float16 h = (_Float16)th;
        sh[v] = h;
        sl[v] = (_Float16)((th - (float)h) * 4096.0f);
      }
    }

    if (!last) {
      // store this lane's 4 features of r(t+1): row lr, cols jb..jb+3 (8B)
      const int soff = (((t + 1) & 1) * 8 + g) * (16 * FDIM) + lr * FDIM + jb;
      *(half4*)(rH + soff) = sh;
      *(half4*)(rL + soff) = sl;
      __threadfence();               // release: drain + make stores agent-visible
      __syncthreads();               // all 4 waves of this WG done
      if (threadIdx.x == 0)
        __hip_atomic_fetch_add(mycnt + t, 1u, __ATOMIC_RELAXED,
                               __HIP_MEMORY_SCOPE_AGENT);
    }
  }
}

extern "C" void kernel_launch(void* const* d_in, const int* in_sizes, int n_in,
                              void* d_out, int out_size, void* d_ws, size_t ws_size,
                              hipStream_t stream) {
  const float* X = (const float*)d_in[0];
  const float* W = (const float*)d_in[1];
  const float* b = (const float*)d_in[2];
  float* out = (float*)d_out;
  char* ws = (char*)d_ws;

  _Float16* WH = (_Float16*)(ws + WS_WH);
  _Float16* WL = (_Float16*)(ws + WS_WL);
  _Float16* rh = (_Float16*)(ws + WS_RH);
  _Float16* rl = (_Float16*)(ws + WS_RL);
  unsigned int* cnt = (unsigned int*)(ws + WS_CNT);

  // zero r state (R0 = 0) and all step counters — re-done every launch (graph-safe)
  hipMemsetAsync(ws + WS_RH, 0, (1600u * 1024u) - WS_RH, stream);
  rnn_prep<<<128, 256, 0, stream>>>(W, WH, WL);
  rnn_main<<<64, 256, 0, stream>>>(X, b, WH, WL, rh, rl, cnt, out);
}

// Round 2
// 8728.715 us; speedup vs baseline: 3.5758x; 3.5758x over previous
//
#include <hip/hip_runtime.h>

#define TSTEPS 2048
#define VDIM 128
#define FDIM 512

typedef __attribute__((ext_vector_type(8))) _Float16 half8;
typedef __attribute__((ext_vector_type(4))) _Float16 half4;
typedef __attribute__((ext_vector_type(4))) float floatx4;

// ws layout (bytes):
//   [0,       512K)  WH  : f16 hi, A-frag order: [wf32][kk16][lane64][e8]
//   [512K,   1024K)  WL  : f16 lo*4096, same order
//   [1024K,  1280K)  rH  : f16 hi   [buf2][g8][row16][k512]
//   [1280K,  1536K)  rL  : f16 lo*4096, same
//   [1536K,  1600K)  cnt : u32 [g8][t2048]
#define WS_WH   0
#define WS_WL   (512u * 1024u)
#define WS_RH   (1024u * 1024u)
#define WS_RL   (1280u * 1024u)
#define WS_CNT  (1536u * 1024u)

// Pre-swizzle W (fp32 row-major [j][k]) into per-wave A-fragment order, split
// into f16 hi + f16 lo*4096.  A-frag (16x16x32): lane l holds row (l&15),
// k = 8*(l>>4) + e within each K=32 block kk.
__global__ __launch_bounds__(256) void rnn_prep(const float* __restrict__ W,
                                                _Float16* __restrict__ WH,
                                                _Float16* __restrict__ WL) {
  int tid = blockIdx.x * 256 + threadIdx.x;   // 0..32767 (32 wf * 16 kk * 64 l)
  int wf = tid >> 10;
  int kk = (tid >> 6) & 15;
  int l  = tid & 63;
  int j  = 16 * wf + (l & 15);
  int k0 = kk * 32 + (l >> 4) * 8;
  const float* src = W + j * FDIM + k0;
  half8 vh, vl;
#pragma unroll
  for (int e = 0; e < 8; ++e) {
    float w = src[e];
    _Float16 h = (_Float16)w;
    vh[e] = h;
    vl[e] = (_Float16)((w - (float)h) * 4096.0f);
  }
  *(half8*)(WH + (size_t)tid * 8) = vh;
  *(half8*)(WL + (size_t)tid * 8) = vl;
}

// 64 WGs = 8 row-groups (g) x 8 feature-slices.  256 thr = 4 waves, each wave
// owns 16 output features (wf), W slice pinned in VGPRs.  Per step: coherent
// (sc0sc1) load of group r into LDS (XOR-swizzled), MFMA, tanh, coherent
// write-through of own slice, counter atomicAdd.  NO cache-flush fences.
__global__ void __launch_bounds__(256, 1)
rnn_main(const float* __restrict__ X, const float* __restrict__ bvec,
         const _Float16* __restrict__ WH, const _Float16* __restrict__ WL,
         _Float16* __restrict__ rH, _Float16* __restrict__ rL,
         unsigned int* __restrict__ cnt, float* __restrict__ out) {
  __shared__ char lds[32768];                 // [0,16K) r-hi, [16K,32K) r-lo
  const int g  = blockIdx.x & 7;
  const int w  = threadIdx.x >> 6;
  const int l  = threadIdx.x & 63;
  const int wf = (blockIdx.x >> 3) * 4 + w;   // 0..31
  const int lr = l & 15;                      // state row within group (D col)
  const int lg = l >> 4;                      // lane group
  const int jb = 16 * wf + lg * 4;            // this lane's 4 features jb..jb+3

  // persistent W fragments (hi + lo): 128 VGPRs, pinned so the compiler
  // cannot re-materialize the loads inside the t-loop.
  const half8* pWh = (const half8*)WH + wf * 16 * 64 + l;
  const half8* pWl = (const half8*)WL + wf * 16 * 64 + l;
#define LW(i) half8 wh##i = pWh[(i) * 64]; half8 wl##i = pWl[(i) * 64]; \
  asm volatile("" : "+v"(wh##i), "+v"(wl##i));
  LW(0) LW(1) LW(2) LW(3) LW(4) LW(5) LW(6) LW(7)
  LW(8) LW(9) LW(10) LW(11) LW(12) LW(13) LW(14) LW(15)
#undef LW

  const floatx4 bv = *(const floatx4*)(bvec + jb);
  unsigned int* mycnt = cnt + g * TSTEPS;
  const bool vis = (wf < 8);
  const bool diagWave = (wf == g);
  int budget = 4000000;

  // swizzled LDS read bases: row lr, byte col cb = kk*64 + lg*16,
  // swz = lr*1024 + (cb ^ ((lr&7)<<4)).  Split XOR bits: x56 (bits 4-5, from
  // lg*16), x6 (bit 6, from kk&1) -> two base pointers + (kk>>1)*128 imm.
  const int x56 = (lr & 3) << 4;
  const int x6  = (lr & 4) << 4;
  const char* const pb0 = lds + lr * 1024 + ((lg * 16) ^ x56) + x6;
  const char* const pb1 = lds + lr * 1024 + ((lg * 16) ^ x56) + (64 ^ x6);

  for (int t = 0; t < TSTEPS; ++t) {
    floatx4 xv = {0.f, 0.f, 0.f, 0.f};
    if (vis) xv = *(const floatx4*)(X + t * VDIM + jb);

    if (t > 0) {
      if ((threadIdx.x & 63) == 0) {
        while (__hip_atomic_load(mycnt + (t - 1), __ATOMIC_RELAXED,
                                 __HIP_MEMORY_SCOPE_AGENT) < 8u) {
          if (--budget < 0) break;
          __builtin_amdgcn_s_sleep(1);
        }
      }
      asm volatile("" ::: "memory");   // keep staging loads after the spin
    }

    // cooperative coherent load of group's r (16K hi + 16K lo) into LDS,
    // XOR-swizzled on the write side.
    {
      const char* gHp = (const char*)(rH + (size_t)((t & 1) * 8 + g) * (16 * FDIM));
      const char* gLp = (const char*)(rL + (size_t)((t & 1) * 8 + g) * (16 * FDIM));
#pragma unroll
      for (int i = 0; i < 8; ++i) {
        int o = (threadIdx.x + 256 * i) * 8;
        unsigned long long vh = __hip_atomic_load(
            (const unsigned long long*)(gHp + o), __ATOMIC_RELAXED,
            __HIP_MEMORY_SCOPE_AGENT);
        unsigned long long vl = __hip_atomic_load(
            (const unsigned long long*)(gLp + o), __ATOMIC_RELAXED,
            __HIP_MEMORY_SCOPE_AGENT);
        int so = o ^ (((o >> 10) & 7) << 4);
        *(unsigned long long*)(lds + so) = vh;
        *(unsigned long long*)(lds + 16384 + so) = vl;
      }
    }
    __syncthreads();

    floatx4 aHH = {0.f,0.f,0.f,0.f}, aLH = {0.f,0.f,0.f,0.f}, aHL = {0.f,0.f,0.f,0.f};
#define KSTEP(i, WH_, WL_) { \
    const char* pb = ((i) & 1) ? pb1 : pb0; \
    half8 bh = *(const half8*)(pb + ((i) >> 1) * 128); \
    half8 bl = *(const half8*)(pb + 16384 + ((i) >> 1) * 128); \
    aHH = __builtin_amdgcn_mfma_f32_16x16x32_f16(WH_, bh, aHH, 0, 0, 0); \
    aLH = __builtin_amdgcn_mfma_f32_16x16x32_f16(WL_, bh, aLH, 0, 0, 0); \
    aHL = __builtin_amdgcn_mfma_f32_16x16x32_f16(WH_, bl, aHL, 0, 0, 0); \
  }
    KSTEP(0, wh0, wl0)  KSTEP(1, wh1, wl1)  KSTEP(2, wh2, wl2)  KSTEP(3, wh3, wl3)
    KSTEP(4, wh4, wl4)  KSTEP(5, wh5, wl5)  KSTEP(6, wh6, wl6)  KSTEP(7, wh7, wl7)
    KSTEP(8, wh8, wl8)  KSTEP(9, wh9, wl9)  KSTEP(10, wh10, wl10) KSTEP(11, wh11, wl11)
    KSTEP(12, wh12, wl12) KSTEP(13, wh13, wl13) KSTEP(14, wh14, wl14) KSTEP(15, wh15, wl15)
#undef KSTEP

    const bool last = (t == TSTEPS - 1);
    half4 sh, sl;
#pragma unroll
    for (int v = 0; v < 4; ++v) {
      float u = (aHH[v] + (aLH[v] + aHL[v]) * 2.44140625e-4f) + bv[v];
      if (vis) {
        float blend = 0.5f * u + 0.5f * xv[v];
        bool isdiag = diagWave && (lg * 4 + v == lr);
        if (!isdiag) u = blend;          // diag: Lambda=1, keep u = WR + b
      }
      if (last) {
        if (diagWave && (lg * 4 + v == lr)) out[16 * g + lr] = u;  // pre-tanh
      } else {
        float au = fabsf(u);
        float e2 = __expf(-2.0f * au);
        float th = __fdividef(1.0f - e2, 1.0f + e2);
        th = copysignf(th, u);
        _Float16 h = (_Float16)th;
        sh[v] = h;
        sl[v] = (_Float16)((th - (float)h) * 4096.0f);
      }
    }

    if (!last) {
      // write-through (sc0sc1) store of this lane's 4 features of r(t+1)
      const size_t soff = (size_t)(((t + 1) & 1) * 8 + g) * (16 * FDIM)
                        + lr * FDIM + jb;
      union { half4 h; unsigned long long u; } ch, cl;
      ch.h = sh; cl.h = sl;
      __hip_atomic_store((unsigned long long*)(rH + soff), ch.u,
                         __ATOMIC_RELAXED, __HIP_MEMORY_SCOPE_AGENT);
      __hip_atomic_store((unsigned long long*)(rL + soff), cl.u,
                         __ATOMIC_RELAXED, __HIP_MEMORY_SCOPE_AGENT);
      asm volatile("s_waitcnt vmcnt(0)" ::: "memory");  // stores globally visible
      __syncthreads();                                  // all 4 waves done
      if (threadIdx.x == 0)
        __hip_atomic_fetch_add(mycnt + t, 1u, __ATOMIC_RELAXED,
                               __HIP_MEMORY_SCOPE_AGENT);
    }
  }
}

extern "C" void kernel_launch(void* const* d_in, const int* in_sizes, int n_in,
                              void* d_out, int out_size, void* d_ws, size_t ws_size,
                              hipStream_t stream) {
  const float* X = (const float*)d_in[0];
  const float* W = (const float*)d_in[1];
  const float* b = (const float*)d_in[2];
  float* out = (float*)d_out;
  char* ws = (char*)d_ws;

  _Float16* WH = (_Float16*)(ws + WS_WH);
  _Float16* WL = (_Float16*)(ws + WS_WL);
  _Float16* rh = (_Float16*)(ws + WS_RH);
  _Float16* rl = (_Float16*)(ws + WS_RL);
  unsigned int* cnt = (unsigned int*)(ws + WS_CNT);

  // zero r state (R0 = 0) and all step counters — re-done every launch
  hipMemsetAsync(ws + WS_RH, 0, (1600u * 1024u) - WS_RH, stream);
  rnn_prep<<<128, 256, 0, stream>>>(W, WH, WL);
  rnn_main<<<64, 256, 0, stream>>>(X, b, WH, WL, rh, rl, cnt, out);
}